// Round 1
// baseline (285.255 us; speedup 1.0000x reference)
//
#include <hip/hip_runtime.h>
#include <stdint.h>

// Scatter-upsample, last-write-wins (largest k):
//   y = zeros((num_nodes,256)); y[col(k), row(k)] = x.flat[k]
//   col(k) = neigh[7*i + max_index[i,f]], k = i*256+f, row(k)=floor(k*256/(T-1)).
//
// R6 theory: old 3-pass touched the 168MB out buffer with TWO random
// scattered rounds (tag atomicMax RMW + value check RMW) just to resolve
// rare collisions. Key structure: row r is produced ONLY by a contiguous
// ~162-node window (node spans 256 k's, row spans ~40962 k's), and per row
// there are at most 162*7 = 1134 candidate cells. So winners can be fully
// resolved in a per-row LDS hash (2048 slots, provably no overflow), with
// zero global atomics, leaving ONE random round of plain stores.
//
// K1: 256 row-WGs (ballot candidate extraction -> LDS hash dedup ->
//     resolved (addr,bits) table in ws) + 1024 zeroer WGs at full write BW.
// K2: read 4MB resolved table, plain scattered stores (fire-and-forget).

#define FEAT 256
#define LOG2FEAT 8
#define BLOCK 256
#define ROW_WGS 256          // one WG per output row r
#define ZERO_WGS 1024
#define HASH 2048            // per-row hash; max 1134 distinct cols < 2048
#define LOG2HASH 11

extern "C" __global__ __launch_bounds__(BLOCK)
void row_build_zero_kernel(const int*   __restrict__ mi,     // int32 0..6
                           const int*   __restrict__ neigh,  // int32
                           const float* __restrict__ x,
                           float*       __restrict__ out,
                           int2*        __restrict__ winners, // [ROW_WGS*HASH]
                           int total,                          // raw_nodes*256
                           int out_elems)                      // num_nodes*256
{
    const int tid = threadIdx.x;

    // ---- zeroer role: saturate HBM write BW while row-WGs build ----------
    if (blockIdx.x >= ROW_WGS) {
        const int zid = blockIdx.x - ROW_WGS;
        float4* out4 = (float4*)out;
        const int total4 = out_elems >> 2;                // exact multiple of 4
        const float4 z = make_float4(0.f, 0.f, 0.f, 0.f);
        for (int idx = zid * BLOCK + tid; idx < total4; idx += ZERO_WGS * BLOCK)
            out4[idx] = z;
        return;
    }

    // ---- row role: resolve all winners for output row r in LDS -----------
    __shared__ int hkey[HASH];   // col, -1 = empty
    __shared__ int hval[HASH];   // max kp1 for that col

    for (int s = tid; s < HASH; s += BLOCK) { hkey[s] = -1; hval[s] = 0; }
    __syncthreads();

    const int r = blockIdx.x;                             // 0..255
    const unsigned tm1 = (unsigned)(total - 1);
    // k-range [klo, khi] of row r:  row(k) = floor(k*256/(T-1)), last clamped
    const unsigned klo = ((unsigned)r * tm1 + 255u) >> 8;
    const unsigned khi = (r == 255) ? (unsigned)(total - 1)
                       : (((unsigned)(r + 1) * tm1 + 255u) >> 8) - 1u;
    const int i0 = (int)(klo >> 8);                       // node window
    const int i1 = (int)(khi >> 8);                       // (~162 nodes)

    const int lane = tid & 63;
    const int wv   = tid >> 6;                            // wave 0..3

    // software pipeline: prefetch first node's mi row
    int p0 = 0, p1 = 0, p2 = 0, p3 = 0;
    {
        const int ifirst = i0 + wv;
        if (ifirst <= i1) {
            const int* mrow = mi + (ifirst << LOG2FEAT);
            p0 = mrow[lane];       p1 = mrow[64 + lane];
            p2 = mrow[128 + lane]; p3 = mrow[192 + lane];
        }
    }

    for (int i = i0 + wv; i <= i1; i += 4) {
        const int m0 = p0, m1 = p1, m2 = p2, m3 = p3;
        const int inx = i + 4;
        if (inx <= i1) {                                  // prefetch next node
            const int* mrow = mi + (inx << LOG2FEAT);
            p0 = mrow[lane];       p1 = mrow[64 + lane];
            p2 = mrow[128 + lane]; p3 = mrow[192 + lane];
        }
        const int mycol = (lane < 7) ? neigh[i * 7 + lane] : 0;

        const int kbase = i << LOG2FEAT;
        // f-window of node i belonging to row r (interior nodes: [0,255])
        int wlo = (int)klo - kbase; if (wlo < 0)   wlo = 0;
        int whi = (int)khi - kbase; if (whi > 255) whi = 255;

        unsigned long long wm[4];
        #pragma unroll
        for (int j = 0; j < 4; ++j) {
            int lo = wlo - j * 64;  if (lo < 0) lo = 0;
            int hi = whi - j * 64 + 1;
            unsigned long long mhi = (hi >= 64) ? ~0ull
                                   : (hi <= 0)  ? 0ull : ((1ull << hi) - 1ull);
            unsigned long long mlo = (lo >= 64) ? ~0ull : ((1ull << lo) - 1ull);
            wm[j] = mhi & ~mlo;
        }

        unsigned long long b[4][7];
        #pragma unroll
        for (int m = 0; m < 7; ++m) {                     // wave-uniform
            b[0][m] = __ballot(m0 == m);
            b[1][m] = __ballot(m1 == m);
            b[2][m] = __ballot(m2 == m);
            b[3][m] = __ballot(m3 == m);
        }

        if (lane < 7) {                                   // lane = m
            const int m = lane;
            int bestf = -1;
            #pragma unroll
            for (int j = 3; j >= 0; --j) {                // const j: regs only
                if (bestf < 0) {
                    unsigned long long s =
                        (m == 0) ? b[j][0] : (m == 1) ? b[j][1] :
                        (m == 2) ? b[j][2] : (m == 3) ? b[j][3] :
                        (m == 4) ? b[j][4] : (m == 5) ? b[j][5] : b[j][6];
                    unsigned long long t = s & wm[j];
                    if (t) bestf = j * 64 + 63 - __clzll(t);
                }
            }
            if (bestf >= 0) {
                const int kp1 = kbase + bestf + 1;        // globally ordered key
                int slot = mycol & (HASH - 1);
                while (true) {                            // CAS-claim, no locks
                    int prev = atomicCAS(&hkey[slot], -1, mycol);
                    if (prev == -1 || prev == mycol) {
                        atomicMax(&hval[slot], kp1);      // LDS atomic: winner
                        break;
                    }
                    slot = (slot + 1) & (HASH - 1);       // <=1134 keys: no wrap-lock
                }
            }
        }
    }

    __syncthreads();

    // emit resolved table; every slot written -> no stale ws state
    for (int s = tid; s < HASH; s += BLOCK) {
        const int key = hkey[s];
        int2 w = make_int2(-1, 0);
        if (key >= 0) {
            const int kp1 = hval[s];
            w.x = (key << LOG2FEAT) | r;                  // out address
            w.y = __float_as_int(x[kp1 - 1]);             // row-local gather
        }
        winners[(r << LOG2HASH) + s] = w;                 // coalesced
    }
}

extern "C" __global__ __launch_bounds__(256)
void scatter_kernel(int* __restrict__ out_i,
                    const int2* __restrict__ winners,
                    int nslots)
{
    for (int idx = blockIdx.x * 256 + threadIdx.x; idx < nslots;
         idx += gridDim.x * 256) {
        const int2 w = winners[idx];
        if (w.x >= 0) out_i[w.x] = w.y;                   // plain store, no RMW read
    }
}

extern "C" void kernel_launch(void* const* d_in, const int* in_sizes, int n_in,
                              void* d_out, int out_size, void* d_ws, size_t ws_size,
                              hipStream_t stream) {
    const float* x     = (const float*)d_in[0];   // f32 (40962, 256)
    const int*   mi    = (const int*)d_in[1];     // int32 (40962, 256), 0..6
    const int*   neigh = (const int*)d_in[2];     // int32 (40962*7,)
    float*       out   = (float*)d_out;

    const int total     = in_sizes[0];            // raw_nodes * 256
    const int out_elems = out_size;               // num_nodes * 256

    int2* winners = (int2*)d_ws;                  // 256*2048*8B = 4 MB

    row_build_zero_kernel<<<dim3(ROW_WGS + ZERO_WGS), dim3(BLOCK), 0, stream>>>(
        mi, neigh, x, out, winners, total, out_elems);
    scatter_kernel<<<dim3(1024), dim3(256), 0, stream>>>(
        (int*)out, winners, ROW_WGS * HASH);
}